// Round 5
// baseline (87.740 us; speedup 1.0000x reference)
//
#include <hip/hip_runtime.h>
#include <math.h>

#define T_LEN 8192
#define EPSF  1e-6f

typedef __attribute__((ext_vector_type(8))) short short8;
typedef __attribute__((ext_vector_type(4))) float float4v;

// ---------------------------------------------------------------------------
// Prep (1 block, 64 threads; ~1 us): znorm each shapelet, bf16 hi/lo split
// (arithmetic bit-identical to the R2/R4 prep), and scatter the results
// DIRECTLY IN MFMA-FRAGMENT ORDER with the column permutation
//   B column c = pt*16 + n  holds logical shapelet p = 4*n + pt
// so the main kernel's epilogue lane n owns 4 CONSECUTIVE output columns
// (4n..4n+3) -> float4 stores.
// Fragment-order layout (short8 units): idx8 = ((pt*2+h)*4 + quad)*16 + n,
// element j (k = 32h + 8*quad + j). Per-shapelet sum / sum-of-squares of the
// EFFECTIVE (hi+lo) values stored in logical-p order (float4-readable).
// ---------------------------------------------------------------------------
__global__ __launch_bounds__(64) void prep_kernel(const float* __restrict__ sh,
                                                  unsigned short* __restrict__ fbhi,
                                                  unsigned short* __restrict__ fblo,
                                                  float* __restrict__ snsum,
                                                  float* __restrict__ s2) {
    const int p = threadIdx.x;           // logical shapelet
    const int n = p >> 2, pt = p & 3;    // its (n, pt) slot under the perm
    float v[64];
    float s1 = 0.f;
    for (int l = 0; l < 64; ++l) { v[l] = sh[p * 64 + l]; s1 += v[l]; }
    float mu = s1 * (1.f / 64.f);
    float sq = 0.f;
    for (int l = 0; l < 64; ++l) { float d = v[l] - mu; sq = fmaf(d, d, sq); }
    float sd  = fmaxf(sqrtf(sq * (1.f / 64.f)), EPSF);
    float inv = 1.f / sd;
    float ssum = 0.f, ss2 = 0.f;
    for (int l = 0; l < 64; ++l) {
        float s = (v[l] - mu) * inv;
        unsigned ub = __float_as_uint(s);
        float hi = __uint_as_float(ub & 0xFFFF0000u);
        float lo = s - hi;
        unsigned lb = __float_as_uint(lo) & 0xFFFF0000u;
        int h = l >> 5, quad = (l >> 3) & 3, j = l & 7;
        int idx = (((pt * 2 + h) * 4 + quad) * 16 + n) * 8 + j;
        fbhi[idx] = (unsigned short)(ub >> 16);
        fblo[idx] = (unsigned short)(lb >> 16);
        float eff = hi + __uint_as_float(lb);   // what the MFMA sees
        ssum += eff;
        ss2  = fmaf(eff, eff, ss2);
    }
    snsum[p] = ssum;   // logical order: lane n reads float4 at 4n
    s2[p]    = ss2;
}

// ---------------------------------------------------------------------------
// Main: one block = (batch b, 128-row t-strip), 2048 blocks, 256 threads.
// B fragments load global->register at kernel top (16 KB set, L1/L2-hot,
// in flight through staging+stats). LDS holds only the x window + per-row
// window stats (~2.5 KB). 3-MFMA bf16 hi/lo GEMM (verbatim R4 numerics);
// epilogue folds the window znorm and stores float4 per row (permuted
// columns make lane n's 4 values contiguous). Rows t<32 / t>8160 = padding.
// ---------------------------------------------------------------------------
__global__ __launch_bounds__(256, 4) void shapelet_mfma(
        const float* __restrict__ x,
        const unsigned short* __restrict__ fbhi,
        const unsigned short* __restrict__ fblo,
        const float* __restrict__ gsum,
        const float* __restrict__ gs2,
        float* __restrict__ out) {
    __shared__ float xs[192];                     // x[t0-32 .. t0+159]
    __shared__ float lmu[128], linv[128], lw2[128];

    const int tid  = threadIdx.x;
    const int lane = tid & 63;
    const int wave = tid >> 6;
    const int n    = lane & 15;
    const int quad = lane >> 4;

    const int super = blockIdx.x & 63;            // 64 strips of 128 rows
    const int b     = blockIdx.x >> 6;            // 32 batches
    const int t0    = super << 7;

    // ---- 1. B fragments + correction vectors: global -> registers ----
    // Per (pt,h): 64 lanes read 64 consecutive short8 = 1 KB coalesced.
    short8 Bh[4][2], Bl[4][2];
    {
        const short8* gh = (const short8*)fbhi;
        const short8* gl = (const short8*)fblo;
#pragma unroll
        for (int pt = 0; pt < 4; ++pt)
#pragma unroll
            for (int h = 0; h < 2; ++h) {
                int idx = ((pt * 2 + h) * 4 + quad) * 16 + n;
                Bh[pt][h] = gh[idx];
                Bl[pt][h] = gl[idx];
            }
    }
    const float4 sm4 = *(const float4*)(gsum + (n << 2));  // lsum[4n..4n+3]
    const float4 sv4 = *(const float4*)(gs2  + (n << 2));  // ls2 [4n..4n+3]

    // ---- 2. stage x window (float4, aligned; edge blocks element-guarded) ----
    if (tid < 48) {
        int g0 = t0 - 32 + (tid << 2);
        float4 v;
        if (g0 >= 0 && g0 + 3 < T_LEN) {
            v = *(const float4*)(x + (size_t)b * T_LEN + g0);
        } else {
            float* vp = (float*)&v;
#pragma unroll
            for (int e = 0; e < 4; ++e) {
                int g = g0 + e;
                vp[e] = ((unsigned)g < (unsigned)T_LEN) ? x[(size_t)b * T_LEN + g] : 0.f;
            }
        }
        *(float4*)&xs[tid << 2] = v;
    }
    __syncthreads();

    // ---- 3. per-row window stats (verbatim R4 math) ----
    if (tid < 128) {
        const int r = tid;
        float s1 = 0.f, sq = 0.f;
#pragma unroll
        for (int l = 0; l < 64; ++l) {
            float v = xs[r + l];
            s1 += v; sq = fmaf(v, v, sq);
        }
        float mu  = s1 * (1.f / 64.f);
        float var = fmaxf(sq * (1.f / 64.f) - mu * mu, 0.f);
        float sd  = fmaxf(sqrtf(var), EPSF);
        float inv = 1.f / sd;
        lmu[r]  = mu;
        linv[r] = inv;
        lw2[r]  = 64.f * var * inv * inv;
    }
    __syncthreads();

    // ---- 4. MFMA + epilogue (verbatim R4 numerics; permuted store cols) ----
#pragma unroll
    for (int u = 0; u < 2; ++u) {
        // A fragments: A[m][k] = xs[u*64 + wave*16 + m + k]
        const int abase = (u << 6) + (wave << 4) + n + (quad << 3);
        short8 Ah[2], Al[2];
#pragma unroll
        for (int h = 0; h < 2; ++h) {
#pragma unroll
            for (int j = 0; j < 8; ++j) {
                float v = xs[abase + h * 32 + j];
                unsigned ub = __float_as_uint(v);
                unsigned hb = ub & 0xFFFF0000u;
                float lo = v - __uint_as_float(hb);
                Ah[h][j] = (short)(ub >> 16);
                Al[h][j] = (short)(__float_as_uint(lo) >> 16);
            }
        }

        float4v acc[4];
#pragma unroll
        for (int pt = 0; pt < 4; ++pt) {
            float4v a = {0.f, 0.f, 0.f, 0.f};
#pragma unroll
            for (int h = 0; h < 2; ++h) {
                a = __builtin_amdgcn_mfma_f32_16x16x32_bf16(Ah[h], Bh[pt][h], a, 0, 0, 0);
                a = __builtin_amdgcn_mfma_f32_16x16x32_bf16(Ah[h], Bl[pt][h], a, 0, 0, 0);
                a = __builtin_amdgcn_mfma_f32_16x16x32_bf16(Al[h], Bh[pt][h], a, 0, 0, 0);
            }
            acc[pt] = a;
        }

        // epilogue: fold window znorm, exp, float4 store at cols 4n..4n+3
#pragma unroll
        for (int r = 0; r < 4; ++r) {
            // C/D layout: col = lane&15, row = quad*4 + r
            int tl = (u << 6) + (wave << 4) + (quad << 2) + r;
            int tg = t0 + tl;
            bool valid = (tg >= 32) && (tg <= 8160);
            float mu  = lmu[tl];
            float inv = linv[tl];
            float w2  = lw2[tl];
            float d0 = (acc[0][r] - mu * sm4.x) * inv;
            float d1 = (acc[1][r] - mu * sm4.y) * inv;
            float d2 = (acc[2][r] - mu * sm4.z) * inv;
            float d3 = (acc[3][r] - mu * sm4.w) * inv;
            float4 o;
            o.x = valid ? __expf(-(w2 + sv4.x - 2.f * d0)) : 0.f;
            o.y = valid ? __expf(-(w2 + sv4.y - 2.f * d1)) : 0.f;
            o.z = valid ? __expf(-(w2 + sv4.z - 2.f * d2)) : 0.f;
            o.w = valid ? __expf(-(w2 + sv4.w - 2.f * d3)) : 0.f;
            *(float4*)(out + (((size_t)(b * T_LEN + tg)) << 6) + (n << 2)) = o;
        }
    }
}

extern "C" void kernel_launch(void* const* d_in, const int* in_sizes, int n_in,
                              void* d_out, int out_size, void* d_ws, size_t ws_size,
                              hipStream_t stream) {
    const float* x  = (const float*)d_in[0];   // (32, 8192, 1)
    const float* sh = (const float*)d_in[1];   // (64, 1, 64)
    float* out = (float*)d_out;                // (32, 8192, 64)

    unsigned short* fbhi = (unsigned short*)d_ws;   // 4096 u16, frag order
    unsigned short* fblo = fbhi + 64 * 64;          // 4096 u16
    float* snsum = (float*)(fblo + 64 * 64);        // 64 f, logical order
    float* s2v   = snsum + 64;                      // 64 f

    prep_kernel<<<1, 64, 0, stream>>>(sh, fbhi, fblo, snsum, s2v);
    shapelet_mfma<<<32 * 64, 256, 0, stream>>>(x, fbhi, fblo, snsum, s2v, out);
}

// Round 6
// 87.375 us; speedup vs baseline: 1.0042x; 1.0042x over previous
//
#include <hip/hip_runtime.h>
#include <math.h>

#define T_LEN 8192
#define EPSF  1e-6f

typedef __attribute__((ext_vector_type(8))) short short8;
typedef __attribute__((ext_vector_type(4))) float float4v;

// ---------------------------------------------------------------------------
// Single fused kernel. One block = (batch b, 128-row t-strip), 2048 blocks.
//
// Phase 0: stage raw shapelets (16 KB, coalesced float4) -> Sraw LDS;
//          stage x window (192 floats) -> xs LDS.
// Phase 1: threads 0-63: one thread per shapelet, SERIAL two-pass znorm +
//          bf16 hi/lo split (bit-identical arithmetic to R2/R4, which passed
//          with 99x margin). B rows written at PERMUTED index c = (p&3)*16 +
//          (p>>2) so that epilogue lane n's 4 accumulators are consecutive
//          output columns 4n..4n+3. Threads 64-191: window stats.
// Phase 2: B fragments -> registers; 3-MFMA bf16 hi/lo GEMM (verbatim);
//          epilogue folds window znorm + exp, then round-trips each wave's
//          16x64 tile through private LDS scratch (reusing Sraw; no barrier,
//          in-wave lgkmcnt ordering) to emit FULLY CONTIGUOUS 1 KB stores
//          (4 KB contiguous per wave per unit) - fill-kernel-like pattern.
// ---------------------------------------------------------------------------
__global__ __launch_bounds__(256, 3) void shapelet_fused(
        const float* __restrict__ x,
        const float* __restrict__ sh,
        float* __restrict__ out) {
    __shared__ union {
        float Sraw[64][65];        // prep staging (phases 0-1)
        float xpose[4][1024];      // per-wave 16x64 store-transpose (phase 2)
    } S;
    __shared__ unsigned short Bhi[64][72];     // 144 B rows: 16B-aligned
    __shared__ unsigned short Blo[64][72];
    __shared__ float xs[192];                  // x[t0-32 .. t0+159]
    __shared__ float lmu[128], linv[128], lw2[128];
    __shared__ __align__(16) float lsum[64];   // logical-p order
    __shared__ __align__(16) float ls2[64];

    const int tid  = threadIdx.x;
    const int lane = tid & 63;
    const int wave = tid >> 6;
    const int n    = lane & 15;
    const int quad = lane >> 4;

    const int super = blockIdx.x & 63;         // 64 strips of 128 rows
    const int b     = blockIdx.x >> 6;         // 32 batches
    const int t0    = super << 7;

    // ---------------- phase 0: staging ----------------
    {
        const float4* g4 = (const float4*)sh;  // 1024 float4 = 4096 floats
#pragma unroll
        for (int i = 0; i < 4; ++i) {
            int idx = tid + (i << 8);
            float4 v = g4[idx];
            int e = idx << 2;
            int row = e >> 6, col = e & 63;
            S.Sraw[row][col + 0] = v.x;
            S.Sraw[row][col + 1] = v.y;
            S.Sraw[row][col + 2] = v.z;
            S.Sraw[row][col + 3] = v.w;
        }
        if (tid < 192) {
            int g = t0 - 32 + tid;
            xs[tid] = ((unsigned)g < (unsigned)T_LEN) ? x[(size_t)b * T_LEN + g] : 0.f;
        }
    }
    __syncthreads();

    // ---------------- phase 1: in-block prep ----------------
    if (tid < 64) {
        // One thread per shapelet: EXACT R2/R4 prep arithmetic (serial order).
        const int p = tid;
        const int c = ((p & 3) << 4) + (p >> 2);   // permuted B row
        float s1 = 0.f;
        for (int l = 0; l < 64; ++l) s1 += S.Sraw[p][l];
        float mu = s1 * (1.f / 64.f);
        float sq = 0.f;
        for (int l = 0; l < 64; ++l) { float d = S.Sraw[p][l] - mu; sq = fmaf(d, d, sq); }
        float sd  = fmaxf(sqrtf(sq * (1.f / 64.f)), EPSF);
        float inv = 1.f / sd;
        float ssum = 0.f, ss2 = 0.f;
        for (int l2 = 0; l2 < 32; ++l2) {
            unsigned pk_h, pk_l;
            {   // element 2*l2 (low half)
                float v = S.Sraw[p][2 * l2];
                float s = (v - mu) * inv;
                unsigned ub = __float_as_uint(s);
                float hi = __uint_as_float(ub & 0xFFFF0000u);
                float lo = s - hi;
                unsigned lb = __float_as_uint(lo) & 0xFFFF0000u;
                pk_h = ub >> 16;
                pk_l = lb >> 16;
                float eff = hi + __uint_as_float(lb);
                ssum += eff;
                ss2  = fmaf(eff, eff, ss2);
            }
            {   // element 2*l2+1 (high half)
                float v = S.Sraw[p][2 * l2 + 1];
                float s = (v - mu) * inv;
                unsigned ub = __float_as_uint(s);
                float hi = __uint_as_float(ub & 0xFFFF0000u);
                float lo = s - hi;
                unsigned lb = __float_as_uint(lo) & 0xFFFF0000u;
                pk_h |= (ub & 0xFFFF0000u);
                pk_l |= lb;
                float eff = hi + __uint_as_float(lb);
                ssum += eff;
                ss2  = fmaf(eff, eff, ss2);
            }
            *(unsigned*)&Bhi[c][2 * l2] = pk_h;
            *(unsigned*)&Blo[c][2 * l2] = pk_l;
        }
        lsum[p] = ssum;
        ls2[p]  = ss2;
    } else if (tid < 192) {
        // per-row window stats (verbatim)
        const int r = tid - 64;
        float s1 = 0.f, sq = 0.f;
#pragma unroll
        for (int l = 0; l < 64; ++l) {
            float v = xs[r + l];
            s1 += v; sq = fmaf(v, v, sq);
        }
        float mu  = s1 * (1.f / 64.f);
        float var = fmaxf(sq * (1.f / 64.f) - mu * mu, 0.f);
        float sd  = fmaxf(sqrtf(var), EPSF);
        float inv = 1.f / sd;
        lmu[r]  = mu;
        linv[r] = inv;
        lw2[r]  = 64.f * var * inv * inv;
    }
    __syncthreads();

    // ---------------- phase 2: MFMA main ----------------
    // B-operand layout: lane holds B[k = quad*8+j + 32*h][col = lane&15];
    // permuted B row c = pt*16+n corresponds to logical shapelet 4n+pt.
    short8 Bh[4][2], Bl[4][2];
#pragma unroll
    for (int pt = 0; pt < 4; ++pt)
#pragma unroll
        for (int h = 0; h < 2; ++h) {
            Bh[pt][h] = *(const short8*)&Bhi[pt * 16 + n][h * 32 + (quad << 3)];
            Bl[pt][h] = *(const short8*)&Blo[pt * 16 + n][h * 32 + (quad << 3)];
        }
    const float4 sm4 = *(const float4*)&lsum[n << 2];   // logical 4n..4n+3
    const float4 sv4 = *(const float4*)&ls2[n << 2];

    float* tile = S.xpose[wave];   // private 16x64 scratch (Sraw is dead now)

#pragma unroll
    for (int u = 0; u < 2; ++u) {
        // A fragments: A[m][k] = xs[u*64 + wave*16 + m + k]
        const int abase = (u << 6) + (wave << 4) + n + (quad << 3);
        short8 Ah[2], Al[2];
#pragma unroll
        for (int h = 0; h < 2; ++h) {
#pragma unroll
            for (int j = 0; j < 8; ++j) {
                float v = xs[abase + h * 32 + j];
                unsigned ub = __float_as_uint(v);
                unsigned hb = ub & 0xFFFF0000u;
                float lo = v - __uint_as_float(hb);
                Ah[h][j] = (short)(ub >> 16);
                Al[h][j] = (short)(__float_as_uint(lo) >> 16);
            }
        }

        float4v acc[4];
#pragma unroll
        for (int pt = 0; pt < 4; ++pt) {
            float4v a = {0.f, 0.f, 0.f, 0.f};
#pragma unroll
            for (int h = 0; h < 2; ++h) {
                a = __builtin_amdgcn_mfma_f32_16x16x32_bf16(Ah[h], Bh[pt][h], a, 0, 0, 0);
                a = __builtin_amdgcn_mfma_f32_16x16x32_bf16(Ah[h], Bl[pt][h], a, 0, 0, 0);
                a = __builtin_amdgcn_mfma_f32_16x16x32_bf16(Al[h], Bh[pt][h], a, 0, 0, 0);
            }
            acc[pt] = a;
        }

        // epilogue: fold window znorm + exp, stage into per-wave LDS tile
#pragma unroll
        for (int r = 0; r < 4; ++r) {
            // C/D layout: col = lane&15, row = quad*4 + r  (within wave tile)
            int rloc = (quad << 2) + r;
            int tl = (u << 6) + (wave << 4) + rloc;
            int tg = t0 + tl;
            bool valid = (tg >= 32) && (tg <= 8160);
            float mu  = lmu[tl];
            float inv = linv[tl];
            float w2  = lw2[tl];
            float d0 = (acc[0][r] - mu * sm4.x) * inv;
            float d1 = (acc[1][r] - mu * sm4.y) * inv;
            float d2 = (acc[2][r] - mu * sm4.z) * inv;
            float d3 = (acc[3][r] - mu * sm4.w) * inv;
            float4 o;
            o.x = valid ? __expf(-(w2 + sv4.x - 2.f * d0)) : 0.f;
            o.y = valid ? __expf(-(w2 + sv4.y - 2.f * d1)) : 0.f;
            o.z = valid ? __expf(-(w2 + sv4.z - 2.f * d2)) : 0.f;
            o.w = valid ? __expf(-(w2 + sv4.w - 2.f * d3)) : 0.f;
            *(float4*)&tile[(rloc << 6) + (n << 2)] = o;
        }

        // in-wave transpose readback: 4 stores, each 1 KB fully contiguous
        // (lane l -> tile row 4s+(l>>4), cols 4(l&15)..+3); no barrier needed
        // (same-wave LDS RAW is lgkmcnt-ordered).
#pragma unroll
        for (int s = 0; s < 4; ++s) {
            float4 v = *(const float4*)&tile[(s << 8) + (lane << 2)];
            int rloc = (s << 2) + (lane >> 4);
            int tg = t0 + (u << 6) + (wave << 4) + rloc;
            int col = (lane & 15) << 2;
            *(float4*)(out + (((size_t)(b * T_LEN + tg)) << 6) + col) = v;
        }
    }
}

extern "C" void kernel_launch(void* const* d_in, const int* in_sizes, int n_in,
                              void* d_out, int out_size, void* d_ws, size_t ws_size,
                              hipStream_t stream) {
    const float* x  = (const float*)d_in[0];   // (32, 8192, 1)
    const float* sh = (const float*)d_in[1];   // (64, 1, 64)
    float* out = (float*)d_out;                // (32, 8192, 64)

    shapelet_fused<<<32 * 64, 256, 0, stream>>>(x, sh, out);
}

// Round 7
// 82.039 us; speedup vs baseline: 1.0695x; 1.0650x over previous
//
#include <hip/hip_runtime.h>
#include <math.h>

#define T_LEN 8192
#define EPSF  1e-6f

typedef __attribute__((ext_vector_type(8))) short short8;
typedef __attribute__((ext_vector_type(4))) float float4v;

// ---------------------------------------------------------------------------
// Single fused kernel. One block = (batch b, 256-row t-strip), 1024 blocks,
// 256 threads, __launch_bounds__(256,4): exactly 4 blocks/CU, ONE dispatch
// round, no tail. Per-block prep + staging amortized over 2x output vs R6.
//
// Phase 0: stage raw shapelets (16 KB float4) -> Sraw; x window (320 f) -> xs.
// Phase 1: threads 0-63: serial two-pass znorm + bf16 hi/lo split per
//          shapelet (bit-identical arithmetic to R2..R6), written at permuted
//          B row c = (p&3)*16 + (p>>2). Threads 64-255: window stats for
//          rows 0..191; threads 64-127 additionally rows 192..255.
// Phase 2: B fragments -> registers (reused across FOUR 64-row units);
//          3-MFMA bf16 hi/lo GEMM; epilogue folds window znorm + exp,
//          direct float4 stores (lane n owns output cols 4n..4n+3).
//          Rows t<32 / t>8160 are the reference's zero padding.
// ---------------------------------------------------------------------------
__global__ __launch_bounds__(256, 4) void shapelet_fused(
        const float* __restrict__ x,
        const float* __restrict__ sh,
        float* __restrict__ out) {
    __shared__ float Sraw[64][65];             // 16.25 KB prep staging
    __shared__ unsigned short Bhi[64][72];     // 9 KB, 144 B rows
    __shared__ unsigned short Blo[64][72];     // 9 KB
    __shared__ float xs[320];                  // x[t0-32 .. t0+287]
    __shared__ float lmu[256], linv[256], lw2[256];   // 3 KB
    __shared__ __align__(16) float lsum[64];   // logical-p order
    __shared__ __align__(16) float ls2[64];

    const int tid  = threadIdx.x;
    const int lane = tid & 63;
    const int wave = tid >> 6;
    const int n    = lane & 15;
    const int quad = lane >> 4;

    const int super = blockIdx.x & 31;         // 32 strips of 256 rows
    const int b     = blockIdx.x >> 5;         // 32 batches
    const int t0    = super << 8;

    // ---------------- phase 0: staging ----------------
    {
        const float4* g4 = (const float4*)sh;  // 1024 float4 = 4096 floats
#pragma unroll
        for (int i = 0; i < 4; ++i) {
            int idx = tid + (i << 8);
            float4 v = g4[idx];
            int e = idx << 2;
            int row = e >> 6, col = e & 63;
            Sraw[row][col + 0] = v.x;
            Sraw[row][col + 1] = v.y;
            Sraw[row][col + 2] = v.z;
            Sraw[row][col + 3] = v.w;
        }
        if (tid < 80) {                        // 80 float4 = 320 floats
            int g0 = t0 - 32 + (tid << 2);
            float4 v;
            if (g0 >= 0 && g0 + 3 < T_LEN) {
                v = *(const float4*)(x + (size_t)b * T_LEN + g0);
            } else {
                float* vp = (float*)&v;
#pragma unroll
                for (int e = 0; e < 4; ++e) {
                    int g = g0 + e;
                    vp[e] = ((unsigned)g < (unsigned)T_LEN) ? x[(size_t)b * T_LEN + g] : 0.f;
                }
            }
            *(float4*)&xs[tid << 2] = v;
        }
    }
    __syncthreads();

    // ---------------- phase 1: in-block prep ----------------
    if (tid < 64) {
        // One thread per shapelet: EXACT R2..R6 prep arithmetic (serial).
        const int p = tid;
        const int c = ((p & 3) << 4) + (p >> 2);   // permuted B row
        float s1 = 0.f;
        for (int l = 0; l < 64; ++l) s1 += Sraw[p][l];
        float mu = s1 * (1.f / 64.f);
        float sq = 0.f;
        for (int l = 0; l < 64; ++l) { float d = Sraw[p][l] - mu; sq = fmaf(d, d, sq); }
        float sd  = fmaxf(sqrtf(sq * (1.f / 64.f)), EPSF);
        float inv = 1.f / sd;
        float ssum = 0.f, ss2 = 0.f;
        for (int l2 = 0; l2 < 32; ++l2) {
            unsigned pk_h, pk_l;
            {   // element 2*l2 (low half)
                float v = Sraw[p][2 * l2];
                float s = (v - mu) * inv;
                unsigned ub = __float_as_uint(s);
                float hi = __uint_as_float(ub & 0xFFFF0000u);
                float lo = s - hi;
                unsigned lb = __float_as_uint(lo) & 0xFFFF0000u;
                pk_h = ub >> 16;
                pk_l = lb >> 16;
                float eff = hi + __uint_as_float(lb);
                ssum += eff;
                ss2  = fmaf(eff, eff, ss2);
            }
            {   // element 2*l2+1 (high half)
                float v = Sraw[p][2 * l2 + 1];
                float s = (v - mu) * inv;
                unsigned ub = __float_as_uint(s);
                float hi = __uint_as_float(ub & 0xFFFF0000u);
                float lo = s - hi;
                unsigned lb = __float_as_uint(lo) & 0xFFFF0000u;
                pk_h |= (ub & 0xFFFF0000u);
                pk_l |= lb;
                float eff = hi + __uint_as_float(lb);
                ssum += eff;
                ss2  = fmaf(eff, eff, ss2);
            }
            *(unsigned*)&Bhi[c][2 * l2] = pk_h;
            *(unsigned*)&Blo[c][2 * l2] = pk_l;
        }
        lsum[p] = ssum;
        ls2[p]  = ss2;
    } else {
        // per-row window stats (verbatim math); threads 64-255 -> rows 0-191,
        // threads 64-127 additionally rows 192-255.
        int r = tid - 64;
#pragma unroll
        for (int pass = 0; pass < 2; ++pass) {
            if (pass == 0 || r < 64 + 192) {   // second pass only for tid<128
                float s1 = 0.f, sq = 0.f;
#pragma unroll
                for (int l = 0; l < 64; ++l) {
                    float v = xs[r + l];
                    s1 += v; sq = fmaf(v, v, sq);
                }
                float mu  = s1 * (1.f / 64.f);
                float var = fmaxf(sq * (1.f / 64.f) - mu * mu, 0.f);
                float sd  = fmaxf(sqrtf(var), EPSF);
                float inv = 1.f / sd;
                lmu[r]  = mu;
                linv[r] = inv;
                lw2[r]  = 64.f * var * inv * inv;
            }
            if (tid >= 128) break;
            r = tid - 64 + 192;                // rows 192..255
            if (pass == 1) break;
        }
    }
    __syncthreads();

    // ---------------- phase 2: MFMA main ----------------
    // B-operand layout: lane holds B[k = quad*8+j + 32*h][col = lane&15];
    // permuted B row c = pt*16+n is logical shapelet 4n+pt.
    short8 Bh[4][2], Bl[4][2];
#pragma unroll
    for (int pt = 0; pt < 4; ++pt)
#pragma unroll
        for (int h = 0; h < 2; ++h) {
            Bh[pt][h] = *(const short8*)&Bhi[pt * 16 + n][h * 32 + (quad << 3)];
            Bl[pt][h] = *(const short8*)&Blo[pt * 16 + n][h * 32 + (quad << 3)];
        }
    const float4 sm4 = *(const float4*)&lsum[n << 2];   // logical 4n..4n+3
    const float4 sv4 = *(const float4*)&ls2[n << 2];

#pragma unroll
    for (int u = 0; u < 4; ++u) {
        // A fragments: A[m][k] = xs[u*64 + wave*16 + m + k]
        const int abase = (u << 6) + (wave << 4) + n + (quad << 3);
        short8 Ah[2], Al[2];
#pragma unroll
        for (int h = 0; h < 2; ++h) {
#pragma unroll
            for (int j = 0; j < 8; ++j) {
                float v = xs[abase + h * 32 + j];
                unsigned ub = __float_as_uint(v);
                unsigned hb = ub & 0xFFFF0000u;
                float lo = v - __uint_as_float(hb);
                Ah[h][j] = (short)(ub >> 16);
                Al[h][j] = (short)(__float_as_uint(lo) >> 16);
            }
        }

        float4v acc[4];
#pragma unroll
        for (int pt = 0; pt < 4; ++pt) {
            float4v a = {0.f, 0.f, 0.f, 0.f};
#pragma unroll
            for (int h = 0; h < 2; ++h) {
                a = __builtin_amdgcn_mfma_f32_16x16x32_bf16(Ah[h], Bh[pt][h], a, 0, 0, 0);
                a = __builtin_amdgcn_mfma_f32_16x16x32_bf16(Ah[h], Bl[pt][h], a, 0, 0, 0);
                a = __builtin_amdgcn_mfma_f32_16x16x32_bf16(Al[h], Bh[pt][h], a, 0, 0, 0);
            }
            acc[pt] = a;
        }

        // epilogue: fold window znorm + exp, float4 store at cols 4n..4n+3
#pragma unroll
        for (int r = 0; r < 4; ++r) {
            // C/D layout: col = lane&15, row = quad*4 + r
            int tl = (u << 6) + (wave << 4) + (quad << 2) + r;
            int tg = t0 + tl;
            bool valid = (tg >= 32) && (tg <= 8160);
            float mu  = lmu[tl];
            float inv = linv[tl];
            float w2  = lw2[tl];
            float d0 = (acc[0][r] - mu * sm4.x) * inv;
            float d1 = (acc[1][r] - mu * sm4.y) * inv;
            float d2 = (acc[2][r] - mu * sm4.z) * inv;
            float d3 = (acc[3][r] - mu * sm4.w) * inv;
            float4 o;
            o.x = valid ? __expf(-(w2 + sv4.x - 2.f * d0)) : 0.f;
            o.y = valid ? __expf(-(w2 + sv4.y - 2.f * d1)) : 0.f;
            o.z = valid ? __expf(-(w2 + sv4.z - 2.f * d2)) : 0.f;
            o.w = valid ? __expf(-(w2 + sv4.w - 2.f * d3)) : 0.f;
            *(float4*)(out + (((size_t)(b * T_LEN + tg)) << 6) + (n << 2)) = o;
        }
    }
}

extern "C" void kernel_launch(void* const* d_in, const int* in_sizes, int n_in,
                              void* d_out, int out_size, void* d_ws, size_t ws_size,
                              hipStream_t stream) {
    const float* x  = (const float*)d_in[0];   // (32, 8192, 1)
    const float* sh = (const float*)d_in[1];   // (64, 1, 64)
    float* out = (float*)d_out;                // (32, 8192, 64)

    shapelet_fused<<<32 * 32, 256, 0, stream>>>(x, sh, out);
}